// Round 7
// baseline (253.123 us; speedup 1.0000x reference)
//
#include <hip/hip_runtime.h>

#define N_NODES 50000
#define N_EDGES 800000
#define IN_SIZE 128
#define HIDDEN 128
#define OUT_SIZE 64

#define CHUNKS 128
#define CHUNK_EDGES 6250      // 128 * 6250 = 800000 exactly
#define GEMMA_TILES 1563      // ceil(50000/32)
#define NBS 196               // ceil(50000/256) block sums, granularity 256 nodes

static __device__ inline unsigned pack_bf16x2(float a, float b) {
    unsigned ua = __float_as_uint(a);
    unsigned ub = __float_as_uint(b);
    unsigned ra = (ua + 0x7fffu + ((ua >> 16) & 1u)) >> 16;        // RNE
    unsigned rb = (ub + 0x7fffu + ((ub >> 16) & 1u)) & 0xffff0000u;
    return ra | rb;
}

static __device__ inline unsigned pack_f16x2(float a, float b) {
    _Float16 ha = (_Float16)a, hb = (_Float16)b;       // RNE converts
    unsigned short ua = __builtin_bit_cast(unsigned short, ha);
    unsigned short ub = __builtin_bit_cast(unsigned short, hb);
    return (unsigned)ua | ((unsigned)ub << 16);
}

static __device__ inline float2 unpack_f16x2(unsigned u) {
    _Float16 lo = __builtin_bit_cast(_Float16, (unsigned short)(u & 0xffffu));
    _Float16 hi = __builtin_bit_cast(_Float16, (unsigned short)(u >> 16));
    return make_float2((float)lo, (float)hi);
}

// ---- chunked LDS histogram: per-chunk dst/src counts + within-chunk rank ----
__global__ __launch_bounds__(1024) void hist_kernel(const int* __restrict__ src,
                                                    const int* __restrict__ dst,
                                                    unsigned char* __restrict__ cntD,
                                                    unsigned char* __restrict__ cntS,
                                                    unsigned char* __restrict__ rp) {
    __shared__ unsigned hD[12500];   // 50000 8-bit counters (dst)
    __shared__ unsigned hS[12500];   // 50000 8-bit counters (src)
    const int t = threadIdx.x;
    const int c = blockIdx.x;

    for (int i = t; i < 12500; i += 1024) { hD[i] = 0u; hS[i] = 0u; }
    __syncthreads();

    const int base = c * CHUNK_EDGES;
    for (int i = t; i < CHUNK_EDGES; i += 1024) {
        int e = base + i;
        int d = dst[e];
        int s = src[e];
        unsigned shd = (unsigned)(d & 3) * 8u;
        unsigned old = atomicAdd(&hD[d >> 2], 1u << shd);
        rp[e] = (unsigned char)((old >> shd) & 0xffu);   // rank within chunk
        atomicAdd(&hS[s >> 2], 1u << ((unsigned)(s & 3) * 8u));
    }
    __syncthreads();

    unsigned* gD = (unsigned*)cntD + (size_t)c * 12500;
    unsigned* gS = (unsigned*)cntS + (size_t)c * 12500;
    for (int i = t; i < 12500; i += 1024) { gD[i] = hD[i]; gS[i] = hS[i]; }
}

// ---------------- GEMM-A: t1 = bf16(h @ W1) ----------------
// LDS-traffic-minimal scheme: W1 (64 KB) staged ONCE per block; A rows are
// wave-uniform and read directly from global (broadcast/scalarizable loads,
// ping-pong prefetched). Inner-loop LDS = one b64 per k (2-way alias = free).
// 4 waves/block x 8 rows/wave = 32 rows/block; each lane owns 2 output cols.
__global__ __launch_bounds__(256) void gemmA_kernel(const float* __restrict__ h,
                                                    const float* __restrict__ W1,
                                                    unsigned short* __restrict__ t1) {
    __shared__ __align__(16) float sW[128][128];   // 64 KB: all of W1
    const int t = threadIdx.x;

    for (int i = t; i < 4096; i += 256)
        ((float4*)sW)[i] = ((const float4*)W1)[i];

    const int wv   = __builtin_amdgcn_readfirstlane(t >> 6);
    const int lane = t & 63;
    const int n0   = blockIdx.x * 32 + wv * 8;     // wave-uniform first row
    const int c0   = lane * 2;

    const float* hr[8];
    #pragma unroll
    for (int r = 0; r < 8; ++r) {
        int gn = n0 + r;
        if (gn > N_NODES - 1) gn = N_NODES - 1;    // clamp; store is guarded
        hr[r] = h + (size_t)gn * 128;
    }

    float4 a_cur[8], a_nxt[8];
    #pragma unroll
    for (int r = 0; r < 8; ++r) a_cur[r] = *(const float4*)(hr[r]);

    __syncthreads();   // sW ready

    float2 acc[8];
    #pragma unroll
    for (int r = 0; r < 8; ++r) acc[r] = make_float2(0.f, 0.f);

    for (int k4 = 0; k4 < 128; k4 += 4) {
        if (k4 + 4 < 128) {
            #pragma unroll
            for (int r = 0; r < 8; ++r) a_nxt[r] = *(const float4*)(hr[r] + k4 + 4);
        }
        #pragma unroll
        for (int kk = 0; kk < 4; ++kk) {
            float2 w = *(const float2*)&sW[k4 + kk][c0];
            #pragma unroll
            for (int r = 0; r < 8; ++r) {
                float a = (kk == 0) ? a_cur[r].x : (kk == 1) ? a_cur[r].y
                        : (kk == 2) ? a_cur[r].z : a_cur[r].w;
                acc[r].x = fmaf(a, w.x, acc[r].x);
                acc[r].y = fmaf(a, w.y, acc[r].y);
            }
        }
        #pragma unroll
        for (int r = 0; r < 8; ++r) a_cur[r] = a_nxt[r];
    }

    #pragma unroll
    for (int r = 0; r < 8; ++r) {
        int gn = n0 + r;
        if (gn < N_NODES) {
            unsigned p = pack_bf16x2(acc[r].x, acc[r].y);
            ((unsigned*)(t1 + (size_t)gn * 128))[lane] = p;
        }
    }
}

// ---- fused: per-node chunk prefix (in-place) + norms + block-level scan ----
__global__ __launch_bounds__(256) void deg_scan_kernel(unsigned char* __restrict__ cntD,
                                                       const unsigned char* __restrict__ cntS,
                                                       int* __restrict__ row_ptr,
                                                       int* __restrict__ bsum,
                                                       float* __restrict__ norm_out,
                                                       float* __restrict__ norm_in) {
    const int t = threadIdx.x, lane = t & 63, w = t >> 6;
    const int n = blockIdx.x * 256 + t;
    unsigned sumD = 0u, sumS = 0u;
    if (n < N_NODES) {
        #pragma unroll 4
        for (int c = 0; c < CHUNKS; ++c) {
            size_t idx = (size_t)c * 50000 + n;
            unsigned v = cntD[idx];
            cntD[idx] = (unsigned char)sumD;   // exclusive prefix (total deg < 256)
            sumD += v;
            sumS += cntS[idx];
        }
        norm_in[n]  = rsqrtf((float)(sumD ? sumD : 1u));
        norm_out[n] = rsqrtf((float)(sumS ? sumS : 1u));
    }
    __shared__ int wsum[4];
    int v = (n < N_NODES) ? (int)sumD : 0;
    int incl = v;
    #pragma unroll
    for (int d = 1; d < 64; d <<= 1) {
        int u = __shfl_up(incl, d, 64);
        if (lane >= d) incl += u;
    }
    if (lane == 63) wsum[w] = incl;
    __syncthreads();
    int woff = 0, total = 0;
    #pragma unroll
    for (int j = 0; j < 4; ++j) {
        int s = wsum[j];
        if (j < w) woff += s;
        total += s;
    }
    if (n < N_NODES) row_ptr[n] = woff + incl - v;
    if (t == 0) bsum[blockIdx.x] = total;
}

// ---- scan of 196 block sums (single wave, chunks with carry) ----
__global__ __launch_bounds__(64) void scan2_kernel(int* __restrict__ bsum,
                                                   int* __restrict__ row_ptr) {
    const int lane = threadIdx.x;
    int carry = 0;
    for (int base = 0; base < NBS; base += 64) {
        int t = base + lane;
        int v = (t < NBS) ? bsum[t] : 0;
        int incl = v;
        #pragma unroll
        for (int d = 1; d < 64; d <<= 1) {
            int u = __shfl_up(incl, d, 64);
            if (lane >= d) incl += u;
        }
        int excl = carry + incl - v;
        if (t < NBS) bsum[t] = excl;
        if (t == NBS - 1) row_ptr[N_NODES] = N_EDGES - excl;
        carry += __shfl(incl, 63, 64);
    }
}

// ---- atomic-free CSR placement: row_ptr + bsum + chunk prefix + rank ----
__global__ __launch_bounds__(256) void place_kernel(const int* __restrict__ src,
                                                    const int* __restrict__ dst,
                                                    const int* __restrict__ row_ptr,
                                                    const int* __restrict__ bsum,
                                                    const unsigned char* __restrict__ cntD,
                                                    const unsigned char* __restrict__ rp,
                                                    int* __restrict__ eidx) {
    int e = blockIdx.x * 256 + threadIdx.x;
    if (e < N_EDGES) {
        int d = dst[e];
        int c = e / CHUNK_EDGES;
        int pos = row_ptr[d] + bsum[d >> 8] + (int)cntD[(size_t)c * 50000 + d] + (int)rp[e];
        eidx[pos] = src[e];
    }
}

// ---------------- GEMM-B: t2 = fp16(h1p @ W2)  (N x 128 @ 128 x 64) ----------------
__global__ __launch_bounds__(256) void gemmB_kernel(const float* __restrict__ h1p,
                                                    const float* __restrict__ W2,
                                                    unsigned short* __restrict__ t2h) {
    __shared__ float sA[32][128];
    __shared__ float sW[128][64];
    const int t  = threadIdx.x;
    const int tx = t & 15;
    const int ty = t >> 4;
    const int n0 = blockIdx.x * 32;

    for (int i = t; i < 1024; i += 256) {
        int n = i >> 5, c = i & 31;
        int gn = n0 + n;
        float4 v = make_float4(0.f, 0.f, 0.f, 0.f);
        if (gn < N_NODES) v = ((const float4*)(h1p + (size_t)gn * 128))[c];
        ((float4*)sA[n])[c] = v;
    }
    for (int i = t; i < 2048; i += 256) {
        int k = i >> 4, c = i & 15;
        ((float4*)sW[k])[c] = ((const float4*)(W2 + (size_t)k * 64))[c];
    }
    __syncthreads();

    float4 a0 = make_float4(0.f, 0.f, 0.f, 0.f);
    float4 a1 = make_float4(0.f, 0.f, 0.f, 0.f);
    #pragma unroll 4
    for (int k4 = 0; k4 < 128; k4 += 4) {
        float x0[4], x1[4];
        *(float4*)x0 = *(const float4*)&sA[ty * 2 + 0][k4];
        *(float4*)x1 = *(const float4*)&sA[ty * 2 + 1][k4];
        #pragma unroll
        for (int kk = 0; kk < 4; ++kk) {
            float4 w = ((float4*)sW[k4 + kk])[tx];
            a0.x = fmaf(x0[kk], w.x, a0.x); a0.y = fmaf(x0[kk], w.y, a0.y);
            a0.z = fmaf(x0[kk], w.z, a0.z); a0.w = fmaf(x0[kk], w.w, a0.w);
            a1.x = fmaf(x1[kk], w.x, a1.x); a1.y = fmaf(x1[kk], w.y, a1.y);
            a1.z = fmaf(x1[kk], w.z, a1.z); a1.w = fmaf(x1[kk], w.w, a1.w);
        }
    }

    #pragma unroll
    for (int ni = 0; ni < 2; ++ni) {
        int gn = n0 + ty * 2 + ni;
        if (gn < N_NODES) {
            float4 a = ni ? a1 : a0;
            uint2 p;
            p.x = pack_f16x2(a.x, a.y);
            p.y = pack_f16x2(a.z, a.w);
            ((uint2*)(t2h + (size_t)gn * 64))[tx] = p;
        }
    }
}

// ---------------- pull aggregation, 128 bf16 feats: one wave per node ----------------
// Batched indices+norms (one vector load + one gather per 64 edges), per-edge
// broadcast via v_readlane; unroll 8 -> 8 gathers in flight per wave.
__global__ __launch_bounds__(256) void pull128_kernel(const unsigned short* __restrict__ xb,
                                                      const int* __restrict__ row_ptr,
                                                      const int* __restrict__ bsum,
                                                      const int* __restrict__ eidx,
                                                      const float* __restrict__ b1,
                                                      const float* __restrict__ norm_in,
                                                      const float* __restrict__ norm_out,
                                                      float* __restrict__ out) {
    int node = blockIdx.x * 4 + (threadIdx.x >> 6);
    node = __builtin_amdgcn_readfirstlane(node);
    const int lane = threadIdx.x & 63;
    const int beg = __builtin_amdgcn_readfirstlane(row_ptr[node] + bsum[node >> 8]);
    const int end = __builtin_amdgcn_readfirstlane(row_ptr[node + 1] + bsum[(node + 1) >> 8]);

    float2 acc0 = make_float2(0.f, 0.f);
    float2 acc1 = make_float2(0.f, 0.f);
    float2 acc2 = make_float2(0.f, 0.f);
    float2 acc3 = make_float2(0.f, 0.f);

    for (int base = beg; base < end; base += 64) {
        const int cnt = min(64, end - base);
        int my_e = 0;
        float my_n = 0.f;
        if (lane < cnt) {
            my_e = eidx[base + lane];
            my_n = norm_out[my_e];
        }
        int k = 0;
        for (; k + 7 < cnt; k += 8) {
            int s0 = __builtin_amdgcn_readlane(my_e, k);
            int s1 = __builtin_amdgcn_readlane(my_e, k + 1);
            int s2 = __builtin_amdgcn_readlane(my_e, k + 2);
            int s3 = __builtin_amdgcn_readlane(my_e, k + 3);
            int s4 = __builtin_amdgcn_readlane(my_e, k + 4);
            int s5 = __builtin_amdgcn_readlane(my_e, k + 5);
            int s6 = __builtin_amdgcn_readlane(my_e, k + 6);
            int s7 = __builtin_amdgcn_readlane(my_e, k + 7);
            float n0 = __int_as_float(__builtin_amdgcn_readlane(__float_as_int(my_n), k));
            float n1 = __int_as_float(__builtin_amdgcn_readlane(__float_as_int(my_n), k + 1));
            float n2 = __int_as_float(__builtin_amdgcn_readlane(__float_as_int(my_n), k + 2));
            float n3 = __int_as_float(__builtin_amdgcn_readlane(__float_as_int(my_n), k + 3));
            float n4 = __int_as_float(__builtin_amdgcn_readlane(__float_as_int(my_n), k + 4));
            float n5 = __int_as_float(__builtin_amdgcn_readlane(__float_as_int(my_n), k + 5));
            float n6 = __int_as_float(__builtin_amdgcn_readlane(__float_as_int(my_n), k + 6));
            float n7 = __int_as_float(__builtin_amdgcn_readlane(__float_as_int(my_n), k + 7));
            unsigned u0 = ((const unsigned*)(xb + (size_t)s0 * 128))[lane];
            unsigned u1 = ((const unsigned*)(xb + (size_t)s1 * 128))[lane];
            unsigned u2 = ((const unsigned*)(xb + (size_t)s2 * 128))[lane];
            unsigned u3 = ((const unsigned*)(xb + (size_t)s3 * 128))[lane];
            unsigned u4 = ((const unsigned*)(xb + (size_t)s4 * 128))[lane];
            unsigned u5 = ((const unsigned*)(xb + (size_t)s5 * 128))[lane];
            unsigned u6 = ((const unsigned*)(xb + (size_t)s6 * 128))[lane];
            unsigned u7 = ((const unsigned*)(xb + (size_t)s7 * 128))[lane];
            acc0.x = fmaf(__uint_as_float(u0 << 16), n0, acc0.x);
            acc0.y = fmaf(__uint_as_float(u0 & 0xffff0000u), n0, acc0.y);
            acc1.x = fmaf(__uint_as_float(u1 << 16), n1, acc1.x);
            acc1.y = fmaf(__uint_as_float(u1 & 0xffff0000u), n1, acc1.y);
            acc2.x = fmaf(__uint_as_float(u2 << 16), n2, acc2.x);
            acc2.y = fmaf(__uint_as_float(u2 & 0xffff0000u), n2, acc2.y);
            acc3.x = fmaf(__uint_as_float(u3 << 16), n3, acc3.x);
            acc3.y = fmaf(__uint_as_float(u3 & 0xffff0000u), n3, acc3.y);
            acc0.x = fmaf(__uint_as_float(u4 << 16), n4, acc0.x);
            acc0.y = fmaf(__uint_as_float(u4 & 0xffff0000u), n4, acc0.y);
            acc1.x = fmaf(__uint_as_float(u5 << 16), n5, acc1.x);
            acc1.y = fmaf(__uint_as_float(u5 & 0xffff0000u), n5, acc1.y);
            acc2.x = fmaf(__uint_as_float(u6 << 16), n6, acc2.x);
            acc2.y = fmaf(__uint_as_float(u6 & 0xffff0000u), n6, acc2.y);
            acc3.x = fmaf(__uint_as_float(u7 << 16), n7, acc3.x);
            acc3.y = fmaf(__uint_as_float(u7 & 0xffff0000u), n7, acc3.y);
        }
        for (; k + 3 < cnt; k += 4) {
            int s0 = __builtin_amdgcn_readlane(my_e, k);
            int s1 = __builtin_amdgcn_readlane(my_e, k + 1);
            int s2 = __builtin_amdgcn_readlane(my_e, k + 2);
            int s3 = __builtin_amdgcn_readlane(my_e, k + 3);
            float n0 = __int_as_float(__builtin_amdgcn_readlane(__float_as_int(my_n), k));
            float n1 = __int_as_float(__builtin_amdgcn_readlane(__float_as_int(my_n), k + 1));
            float n2 = __int_as_float(__builtin_amdgcn_readlane(__float_as_int(my_n), k + 2));
            float n3 = __int_as_float(__builtin_amdgcn_readlane(__float_as_int(my_n), k + 3));
            unsigned u0 = ((const unsigned*)(xb + (size_t)s0 * 128))[lane];
            unsigned u1 = ((const unsigned*)(xb + (size_t)s1 * 128))[lane];
            unsigned u2 = ((const unsigned*)(xb + (size_t)s2 * 128))[lane];
            unsigned u3 = ((const unsigned*)(xb + (size_t)s3 * 128))[lane];
            acc0.x = fmaf(__uint_as_float(u0 << 16), n0, acc0.x);
            acc0.y = fmaf(__uint_as_float(u0 & 0xffff0000u), n0, acc0.y);
            acc1.x = fmaf(__uint_as_float(u1 << 16), n1, acc1.x);
            acc1.y = fmaf(__uint_as_float(u1 & 0xffff0000u), n1, acc1.y);
            acc2.x = fmaf(__uint_as_float(u2 << 16), n2, acc2.x);
            acc2.y = fmaf(__uint_as_float(u2 & 0xffff0000u), n2, acc2.y);
            acc3.x = fmaf(__uint_as_float(u3 << 16), n3, acc3.x);
            acc3.y = fmaf(__uint_as_float(u3 & 0xffff0000u), n3, acc3.y);
        }
        for (; k < cnt; ++k) {
            int s0 = __builtin_amdgcn_readlane(my_e, k);
            float n0 = __int_as_float(__builtin_amdgcn_readlane(__float_as_int(my_n), k));
            unsigned u0 = ((const unsigned*)(xb + (size_t)s0 * 128))[lane];
            acc0.x = fmaf(__uint_as_float(u0 << 16), n0, acc0.x);
            acc0.y = fmaf(__uint_as_float(u0 & 0xffff0000u), n0, acc0.y);
        }
    }

    float ni = norm_in[node];
    float no = norm_out[node];
    float2 bb = ((const float2*)b1)[lane];
    float sx = (acc0.x + acc1.x) + (acc2.x + acc3.x);
    float sy = (acc0.y + acc1.y) + (acc2.y + acc3.y);
    float2 r;
    r.x = fmaxf(fmaf(sx, ni, bb.x), 0.f) * no;
    r.y = fmaxf(fmaf(sy, ni, bb.y), 0.f) * no;
    ((float2*)(out + (size_t)node * 128))[lane] = r;
}

// ---------------- pull aggregation, 64 fp16 feats, 2 edges per wave-round ----------------
// lanes 0-31: edge a, lanes 32-63: edge b; each lane loads 1 uint = 2 halves.
__global__ __launch_bounds__(256) void pull64_kernel(const unsigned* __restrict__ x,
                                                     const int* __restrict__ row_ptr,
                                                     const int* __restrict__ bsum,
                                                     const int* __restrict__ eidx,
                                                     const float* __restrict__ b2,
                                                     const float* __restrict__ norm_in,
                                                     float* __restrict__ out) {
    int node = blockIdx.x * 4 + (threadIdx.x >> 6);
    node = __builtin_amdgcn_readfirstlane(node);
    const int lane = threadIdx.x & 63;
    const int half = lane >> 5;
    const int fl = lane & 31;
    const int beg = __builtin_amdgcn_readfirstlane(row_ptr[node] + bsum[node >> 8]);
    const int end = __builtin_amdgcn_readfirstlane(row_ptr[node + 1] + bsum[(node + 1) >> 8]);

    float2 a0 = make_float2(0.f, 0.f);
    float2 a1 = make_float2(0.f, 0.f);
    float2 a2 = make_float2(0.f, 0.f);
    float2 a3 = make_float2(0.f, 0.f);

    for (int base = beg; base < end; base += 64) {
        const int cnt = min(64, end - base);
        int my_e = (lane < cnt) ? eidx[base + lane] : 0;
        int k = 0;
        for (; k + 7 < cnt; k += 8) {
            int sa0 = __builtin_amdgcn_readlane(my_e, k);
            int sb0 = __builtin_amdgcn_readlane(my_e, k + 1);
            int sa1 = __builtin_amdgcn_readlane(my_e, k + 2);
            int sb1 = __builtin_amdgcn_readlane(my_e, k + 3);
            int sa2 = __builtin_amdgcn_readlane(my_e, k + 4);
            int sb2 = __builtin_amdgcn_readlane(my_e, k + 5);
            int sa3 = __builtin_amdgcn_readlane(my_e, k + 6);
            int sb3 = __builtin_amdgcn_readlane(my_e, k + 7);
            int e0 = half ? sb0 : sa0;
            int e1 = half ? sb1 : sa1;
            int e2 = half ? sb2 : sa2;
            int e3 = half ? sb3 : sa3;
            unsigned u0 = x[(size_t)e0 * 32 + fl];
            unsigned u1 = x[(size_t)e1 * 32 + fl];
            unsigned u2 = x[(size_t)e2 * 32 + fl];
            unsigned u3 = x[(size_t)e3 * 32 + fl];
            float2 v0 = unpack_f16x2(u0);
            float2 v1 = unpack_f16x2(u1);
            float2 v2 = unpack_f16x2(u2);
            float2 v3 = unpack_f16x2(u3);
            a0.x += v0.x; a0.y += v0.y;
            a1.x += v1.x; a1.y += v1.y;
            a2.x += v2.x; a2.y += v2.y;
            a3.x += v3.x; a3.y += v3.y;
        }
        for (; k + 1 < cnt; k += 2) {
            int sa = __builtin_amdgcn_readlane(my_e, k);
            int sb = __builtin_amdgcn_readlane(my_e, k + 1);
            int e0 = half ? sb : sa;
            unsigned u = x[(size_t)e0 * 32 + fl];
            float2 v = unpack_f16x2(u);
            a0.x += v.x; a0.y += v.y;
        }
        if (k < cnt) {
            int sa = __builtin_amdgcn_readlane(my_e, k);
            if (half == 0) {
                unsigned u = x[(size_t)sa * 32 + fl];
                float2 v = unpack_f16x2(u);
                a0.x += v.x; a0.y += v.y;
            }
        }
    }

    float ax = (a0.x + a1.x) + (a2.x + a3.x);
    float ay = (a0.y + a1.y) + (a2.y + a3.y);
    ax += __shfl_xor(ax, 32, 64);
    ay += __shfl_xor(ay, 32, 64);
    if (half == 0) {
        float ni = norm_in[node];
        float2 bb = ((const float2*)b2)[fl];
        float2 r;
        r.x = fmaxf(fmaf(ax, ni, bb.x), 0.f);
        r.y = fmaxf(fmaf(ay, ni, bb.y), 0.f);
        ((float2*)(out + (size_t)node * 64))[fl] = r;
    }
}

extern "C" void kernel_launch(void* const* d_in, const int* in_sizes, int n_in,
                              void* d_out, int out_size, void* d_ws, size_t ws_size,
                              hipStream_t stream) {
    const float* h  = (const float*)d_in[0];
    const float* W1 = (const float*)d_in[1];
    const float* b1 = (const float*)d_in[2];
    const float* W2 = (const float*)d_in[3];
    const float* b2 = (const float*)d_in[4];
    const int* src  = (const int*)d_in[5];
    const int* dst  = (const int*)d_in[6];
    float* out = (float*)d_out;

    char* ws = (char*)d_ws;
    size_t off = 0;
    auto alloc = [&](size_t bytes) {
        void* p = ws + off;
        off = (off + bytes + 255) & ~(size_t)255;
        return p;
    };
    float* norm_out   = (float*)alloc(N_NODES * sizeof(float));
    float* norm_in    = (float*)alloc(N_NODES * sizeof(float));
    int* row_ptr      = (int*)alloc((N_NODES + 1) * sizeof(int));
    int* bsum         = (int*)alloc(NBS * sizeof(int));
    int* eidx         = (int*)alloc((size_t)N_EDGES * sizeof(int));                       // 3.2 MB
    unsigned short* t1 = (unsigned short*)alloc((size_t)N_NODES * 128 * sizeof(short));   // 12.8 MB bf16 (reused as fp16 t2)
    float* h1p        = (float*)alloc((size_t)N_NODES * 128 * sizeof(float));             // 25.6 MB

    // hist/prefix scratch aliases into h1p (dead until pull128 writes h1p):
    unsigned char* cntD = (unsigned char*)h1p;                    // 128 * 50000 = 6.4 MB
    unsigned char* cntS = cntD + (size_t)CHUNKS * 50000;          // 6.4 MB
    unsigned char* rp   = cntS + (size_t)CHUNKS * 50000;          // 0.8 MB
    unsigned short* t2h = t1;    // t1 dead after pull128; 50000*64*2 = 6.4 MB fits

    // degree/rank histograms (LDS atomics, no global atomics)
    hist_kernel<<<CHUNKS, 1024, 0, stream>>>(src, dst, cntD, cntS, rp);

    // t1 = bf16(h @ W1)
    gemmA_kernel<<<GEMMA_TILES, 256, 0, stream>>>(h, W1, t1);

    // per-node chunk prefix + norms + block scan -> partial row_ptr + bsum
    deg_scan_kernel<<<NBS, 256, 0, stream>>>(cntD, cntS, row_ptr, bsum, norm_out, norm_in);

    // scan of block sums (also writes row_ptr[N_NODES])
    scan2_kernel<<<1, 64, 0, stream>>>(bsum, row_ptr);

    // atomic-free CSR placement
    place_kernel<<<(N_EDGES + 255) / 256, 256, 0, stream>>>(src, dst, row_ptr, bsum, cntD, rp, eidx);

    // layer 1 pull (bf16 gather; per-edge norm via readlane broadcast)
    pull128_kernel<<<N_NODES / 4, 256, 0, stream>>>(t1, row_ptr, bsum, eidx, b1,
                                                    norm_in, norm_out, h1p);

    // layer 2
    gemmB_kernel<<<(N_NODES + 31) / 32, 256, 0, stream>>>(h1p, W2, t2h);
    pull64_kernel<<<N_NODES / 4, 256, 0, stream>>>((const unsigned*)t2h, row_ptr, bsum, eidx,
                                                   b2, norm_in, out);
}

// Round 8
// 214.638 us; speedup vs baseline: 1.1793x; 1.1793x over previous
//
#include <hip/hip_runtime.h>

#define N_NODES 50000
#define N_EDGES 800000
#define IN_SIZE 128
#define HIDDEN 128
#define OUT_SIZE 64

#define CHUNKS 128
#define CHUNK_EDGES 6250      // 128 * 6250 = 800000 exactly
#define NBS 196               // ceil(50000/256) block sums, granularity 256 nodes
#define GA_BLOCKS 391         // ceil(50000/128) rows, 128 rows/block (4 waves x 32)

typedef __attribute__((ext_vector_type(8))) short bf16x8;
typedef __attribute__((ext_vector_type(4))) float f32x4;

static __device__ inline unsigned short bf16_rne(float x) {
    unsigned ua = __float_as_uint(x);
    return (unsigned short)((ua + 0x7fffu + ((ua >> 16) & 1u)) >> 16);
}

static __device__ inline unsigned pack_bf16x2(float a, float b) {
    unsigned ua = __float_as_uint(a);
    unsigned ub = __float_as_uint(b);
    unsigned ra = (ua + 0x7fffu + ((ua >> 16) & 1u)) >> 16;        // RNE
    unsigned rb = (ub + 0x7fffu + ((ub >> 16) & 1u)) & 0xffff0000u;
    return ra | rb;
}

static __device__ inline unsigned pack_f16x2(float a, float b) {
    _Float16 ha = (_Float16)a, hb = (_Float16)b;       // RNE converts
    unsigned short ua = __builtin_bit_cast(unsigned short, ha);
    unsigned short ub = __builtin_bit_cast(unsigned short, hb);
    return (unsigned)ua | ((unsigned)ub << 16);
}

static __device__ inline float2 unpack_f16x2(unsigned u) {
    _Float16 lo = __builtin_bit_cast(_Float16, (unsigned short)(u & 0xffffu));
    _Float16 hi = __builtin_bit_cast(_Float16, (unsigned short)(u >> 16));
    return make_float2((float)lo, (float)hi);
}

// ---- W1 fragment pre-pack: Wfrag[ks][ct][lane][j], bf16 hi+lo planes ----
// Bijection: lane (col = l&15, g = l>>4) slot j holds W1[ks*32 + g*8 + j][ct*16 + col].
// A-frags use the same (g,j)->k map, so the MFMA dot product covers k exactly once.
__global__ __launch_bounds__(256) void wpack_kernel(const float* __restrict__ W1,
                                                    unsigned short* __restrict__ wf_hi,
                                                    unsigned short* __restrict__ wf_lo) {
    int idx = blockIdx.x * 256 + threadIdx.x;   // (ks,ct,l): 4*8*64 = 2048
    if (idx >= 2048) return;
    int l  = idx & 63;
    int ct = (idx >> 6) & 7;
    int ks = idx >> 9;
    int col = ct * 16 + (l & 15);
    int k0  = ks * 32 + (l >> 4) * 8;
    unsigned short hi[8], lo[8];
    #pragma unroll
    for (int j = 0; j < 8; ++j) {
        float x = W1[(size_t)(k0 + j) * 128 + col];
        unsigned short h16 = bf16_rne(x);
        float fh = __uint_as_float((unsigned)h16 << 16);
        hi[j] = h16;
        lo[j] = bf16_rne(x - fh);
    }
    ((uint4*)wf_hi)[idx] = *(const uint4*)hi;
    ((uint4*)wf_lo)[idx] = *(const uint4*)lo;
}

// ---------------- GEMM-A via MFMA (bf16x3): t1 = bf16(h @ W1) ----------------
// 4 waves/block, 32 rows/wave (2 row-tiles of 16), 8 col-tiles, K = 4 steps of 32.
// No LDS: A from global (fp32 -> bf16 hi/lo in-register), B-frags from packed
// L2-resident Wfrag (1 KB coalesced per load). acc += a_lo*b_hi + a_hi*b_lo + a_hi*b_hi.
__global__ __launch_bounds__(256) void gemmA_kernel(const float* __restrict__ h,
                                                    const unsigned short* __restrict__ wf_hi,
                                                    const unsigned short* __restrict__ wf_lo,
                                                    unsigned short* __restrict__ t1) {
    const int t  = threadIdx.x;
    const int wv = t >> 6;
    const int l  = t & 63;
    const int lrow = l & 15;
    const int g    = l >> 4;
    const int n0 = blockIdx.x * 128 + wv * 32;

    int r0 = n0 + lrow;      if (r0 > N_NODES - 1) r0 = N_NODES - 1;
    int r1 = n0 + 16 + lrow; if (r1 > N_NODES - 1) r1 = N_NODES - 1;
    const float* h0 = h + (size_t)r0 * 128 + g * 8;
    const float* h1 = h + (size_t)r1 * 128 + g * 8;

    f32x4 acc[2][8];
    #pragma unroll
    for (int rt = 0; rt < 2; ++rt)
        #pragma unroll
        for (int ct = 0; ct < 8; ++ct)
            acc[rt][ct] = (f32x4){0.f, 0.f, 0.f, 0.f};

    const bf16x8* bh_base = (const bf16x8*)wf_hi;
    const bf16x8* bl_base = (const bf16x8*)wf_lo;

    for (int ks = 0; ks < 4; ++ks) {
        float a0[8], a1[8];
        *(float4*)(a0)     = *(const float4*)(h0 + ks * 32);
        *(float4*)(a0 + 4) = *(const float4*)(h0 + ks * 32 + 4);
        *(float4*)(a1)     = *(const float4*)(h1 + ks * 32);
        *(float4*)(a1 + 4) = *(const float4*)(h1 + ks * 32 + 4);

        bf16x8 a0h, a0l, a1h, a1l;
        #pragma unroll
        for (int j = 0; j < 8; ++j) {
            unsigned short hh = bf16_rne(a0[j]);
            a0h[j] = (short)hh;
            a0l[j] = (short)bf16_rne(a0[j] - __uint_as_float((unsigned)hh << 16));
            unsigned short h2 = bf16_rne(a1[j]);
            a1h[j] = (short)h2;
            a1l[j] = (short)bf16_rne(a1[j] - __uint_as_float((unsigned)h2 << 16));
        }

        #pragma unroll
        for (int ct = 0; ct < 8; ++ct) {
            const int fi = (ks * 8 + ct) * 64 + l;
            bf16x8 bh = bh_base[fi];
            bf16x8 bl = bl_base[fi];
            acc[0][ct] = __builtin_amdgcn_mfma_f32_16x16x32_bf16(a0l, bh, acc[0][ct], 0, 0, 0);
            acc[0][ct] = __builtin_amdgcn_mfma_f32_16x16x32_bf16(a0h, bl, acc[0][ct], 0, 0, 0);
            acc[0][ct] = __builtin_amdgcn_mfma_f32_16x16x32_bf16(a0h, bh, acc[0][ct], 0, 0, 0);
            acc[1][ct] = __builtin_amdgcn_mfma_f32_16x16x32_bf16(a1l, bh, acc[1][ct], 0, 0, 0);
            acc[1][ct] = __builtin_amdgcn_mfma_f32_16x16x32_bf16(a1h, bl, acc[1][ct], 0, 0, 0);
            acc[1][ct] = __builtin_amdgcn_mfma_f32_16x16x32_bf16(a1h, bh, acc[1][ct], 0, 0, 0);
        }
    }

    // C/D layout (HW-verified): col = lane&15, row = (lane>>4)*4 + reg
    #pragma unroll
    for (int rt = 0; rt < 2; ++rt) {
        #pragma unroll
        for (int ct = 0; ct < 8; ++ct) {
            #pragma unroll
            for (int r = 0; r < 4; ++r) {
                int row = n0 + rt * 16 + g * 4 + r;
                if (row < N_NODES)
                    t1[(size_t)row * 128 + ct * 16 + lrow] = bf16_rne(acc[rt][ct][r]);
            }
        }
    }
}

// ---- chunked LDS histogram: per-chunk dst/src counts + within-chunk rank ----
__global__ __launch_bounds__(1024) void hist_kernel(const int* __restrict__ src,
                                                    const int* __restrict__ dst,
                                                    unsigned char* __restrict__ cntD,
                                                    unsigned char* __restrict__ cntS,
                                                    unsigned char* __restrict__ rp) {
    __shared__ unsigned hD[12500];   // 50000 8-bit counters (dst)
    __shared__ unsigned hS[12500];   // 50000 8-bit counters (src)
    const int t = threadIdx.x;
    const int c = blockIdx.x;

    for (int i = t; i < 12500; i += 1024) { hD[i] = 0u; hS[i] = 0u; }
    __syncthreads();

    const int base = c * CHUNK_EDGES;
    for (int i = t; i < CHUNK_EDGES; i += 1024) {
        int e = base + i;
        int d = dst[e];
        int s = src[e];
        unsigned shd = (unsigned)(d & 3) * 8u;
        unsigned old = atomicAdd(&hD[d >> 2], 1u << shd);
        rp[e] = (unsigned char)((old >> shd) & 0xffu);   // rank within chunk
        atomicAdd(&hS[s >> 2], 1u << ((unsigned)(s & 3) * 8u));
    }
    __syncthreads();

    unsigned* gD = (unsigned*)cntD + (size_t)c * 12500;
    unsigned* gS = (unsigned*)cntS + (size_t)c * 12500;
    for (int i = t; i < 12500; i += 1024) { gD[i] = hD[i]; gS[i] = hS[i]; }
}

// ---- fused: per-node chunk prefix (in-place) + norms + block-level scan ----
__global__ __launch_bounds__(256) void deg_scan_kernel(unsigned char* __restrict__ cntD,
                                                       const unsigned char* __restrict__ cntS,
                                                       int* __restrict__ row_ptr,
                                                       int* __restrict__ bsum,
                                                       float* __restrict__ norm_out,
                                                       float* __restrict__ norm_in) {
    const int t = threadIdx.x, lane = t & 63, w = t >> 6;
    const int n = blockIdx.x * 256 + t;
    unsigned sumD = 0u, sumS = 0u;
    if (n < N_NODES) {
        #pragma unroll 4
        for (int c = 0; c < CHUNKS; ++c) {
            size_t idx = (size_t)c * 50000 + n;
            unsigned v = cntD[idx];
            cntD[idx] = (unsigned char)sumD;   // exclusive prefix (total deg < 256)
            sumD += v;
            sumS += cntS[idx];
        }
        norm_in[n]  = rsqrtf((float)(sumD ? sumD : 1u));
        norm_out[n] = rsqrtf((float)(sumS ? sumS : 1u));
    }
    __shared__ int wsum[4];
    int v = (n < N_NODES) ? (int)sumD : 0;
    int incl = v;
    #pragma unroll
    for (int d = 1; d < 64; d <<= 1) {
        int u = __shfl_up(incl, d, 64);
        if (lane >= d) incl += u;
    }
    if (lane == 63) wsum[w] = incl;
    __syncthreads();
    int woff = 0, total = 0;
    #pragma unroll
    for (int j = 0; j < 4; ++j) {
        int s = wsum[j];
        if (j < w) woff += s;
        total += s;
    }
    if (n < N_NODES) row_ptr[n] = woff + incl - v;
    if (t == 0) bsum[blockIdx.x] = total;
}

// ---- scan of 196 block sums (single wave, chunks with carry) ----
__global__ __launch_bounds__(64) void scan2_kernel(int* __restrict__ bsum,
                                                   int* __restrict__ row_ptr) {
    const int lane = threadIdx.x;
    int carry = 0;
    for (int base = 0; base < NBS; base += 64) {
        int t = base + lane;
        int v = (t < NBS) ? bsum[t] : 0;
        int incl = v;
        #pragma unroll
        for (int d = 1; d < 64; d <<= 1) {
            int u = __shfl_up(incl, d, 64);
            if (lane >= d) incl += u;
        }
        int excl = carry + incl - v;
        if (t < NBS) bsum[t] = excl;
        if (t == NBS - 1) row_ptr[N_NODES] = N_EDGES - excl;
        carry += __shfl(incl, 63, 64);
    }
}

// ---- atomic-free CSR placement: row_ptr + bsum + chunk prefix + rank ----
__global__ __launch_bounds__(256) void place_kernel(const int* __restrict__ src,
                                                    const int* __restrict__ dst,
                                                    const int* __restrict__ row_ptr,
                                                    const int* __restrict__ bsum,
                                                    const unsigned char* __restrict__ cntD,
                                                    const unsigned char* __restrict__ rp,
                                                    int* __restrict__ eidx) {
    int e = blockIdx.x * 256 + threadIdx.x;
    if (e < N_EDGES) {
        int d = dst[e];
        int c = e / CHUNK_EDGES;
        int pos = row_ptr[d] + bsum[d >> 8] + (int)cntD[(size_t)c * 50000 + d] + (int)rp[e];
        eidx[pos] = src[e];
    }
}

// ---------------- GEMM-B: t2 = fp16(h1p @ W2)  (N x 128 @ 128 x 64) ----------------
__global__ __launch_bounds__(256) void gemmB_kernel(const float* __restrict__ h1p,
                                                    const float* __restrict__ W2,
                                                    unsigned short* __restrict__ t2h) {
    __shared__ float sA[32][128];
    __shared__ float sW[128][64];
    const int t  = threadIdx.x;
    const int tx = t & 15;
    const int ty = t >> 4;
    const int n0 = blockIdx.x * 32;

    for (int i = t; i < 1024; i += 256) {
        int n = i >> 5, c = i & 31;
        int gn = n0 + n;
        float4 v = make_float4(0.f, 0.f, 0.f, 0.f);
        if (gn < N_NODES) v = ((const float4*)(h1p + (size_t)gn * 128))[c];
        ((float4*)sA[n])[c] = v;
    }
    for (int i = t; i < 2048; i += 256) {
        int k = i >> 4, c = i & 15;
        ((float4*)sW[k])[c] = ((const float4*)(W2 + (size_t)k * 64))[c];
    }
    __syncthreads();

    float4 a0 = make_float4(0.f, 0.f, 0.f, 0.f);
    float4 a1 = make_float4(0.f, 0.f, 0.f, 0.f);
    #pragma unroll 4
    for (int k4 = 0; k4 < 128; k4 += 4) {
        float x0[4], x1[4];
        *(float4*)x0 = *(const float4*)&sA[ty * 2 + 0][k4];
        *(float4*)x1 = *(const float4*)&sA[ty * 2 + 1][k4];
        #pragma unroll
        for (int kk = 0; kk < 4; ++kk) {
            float4 w = ((float4*)sW[k4 + kk])[tx];
            a0.x = fmaf(x0[kk], w.x, a0.x); a0.y = fmaf(x0[kk], w.y, a0.y);
            a0.z = fmaf(x0[kk], w.z, a0.z); a0.w = fmaf(x0[kk], w.w, a0.w);
            a1.x = fmaf(x1[kk], w.x, a1.x); a1.y = fmaf(x1[kk], w.y, a1.y);
            a1.z = fmaf(x1[kk], w.z, a1.z); a1.w = fmaf(x1[kk], w.w, a1.w);
        }
    }

    #pragma unroll
    for (int ni = 0; ni < 2; ++ni) {
        int gn = n0 + ty * 2 + ni;
        if (gn < N_NODES) {
            float4 a = ni ? a1 : a0;
            uint2 p;
            p.x = pack_f16x2(a.x, a.y);
            p.y = pack_f16x2(a.z, a.w);
            ((uint2*)(t2h + (size_t)gn * 64))[tx] = p;
        }
    }
}

// ---------------- pull aggregation, 128 bf16 feats: one wave per node ----------------
__global__ __launch_bounds__(256) void pull128_kernel(const unsigned short* __restrict__ xb,
                                                      const int* __restrict__ row_ptr,
                                                      const int* __restrict__ bsum,
                                                      const int* __restrict__ eidx,
                                                      const float* __restrict__ b1,
                                                      const float* __restrict__ norm_in,
                                                      const float* __restrict__ norm_out,
                                                      float* __restrict__ out) {
    int node = blockIdx.x * 4 + (threadIdx.x >> 6);
    node = __builtin_amdgcn_readfirstlane(node);
    const int lane = threadIdx.x & 63;
    const int beg = __builtin_amdgcn_readfirstlane(row_ptr[node] + bsum[node >> 8]);
    const int end = __builtin_amdgcn_readfirstlane(row_ptr[node + 1] + bsum[(node + 1) >> 8]);

    float2 acc0 = make_float2(0.f, 0.f);
    float2 acc1 = make_float2(0.f, 0.f);
    float2 acc2 = make_float2(0.f, 0.f);
    float2 acc3 = make_float2(0.f, 0.f);

    for (int base = beg; base < end; base += 64) {
        const int cnt = min(64, end - base);
        int my_e = 0;
        float my_n = 0.f;
        if (lane < cnt) {
            my_e = eidx[base + lane];
            my_n = norm_out[my_e];
        }
        int k = 0;
        for (; k + 7 < cnt; k += 8) {
            int s0 = __builtin_amdgcn_readlane(my_e, k);
            int s1 = __builtin_amdgcn_readlane(my_e, k + 1);
            int s2 = __builtin_amdgcn_readlane(my_e, k + 2);
            int s3 = __builtin_amdgcn_readlane(my_e, k + 3);
            int s4 = __builtin_amdgcn_readlane(my_e, k + 4);
            int s5 = __builtin_amdgcn_readlane(my_e, k + 5);
            int s6 = __builtin_amdgcn_readlane(my_e, k + 6);
            int s7 = __builtin_amdgcn_readlane(my_e, k + 7);
            float n0 = __int_as_float(__builtin_amdgcn_readlane(__float_as_int(my_n), k));
            float n1 = __int_as_float(__builtin_amdgcn_readlane(__float_as_int(my_n), k + 1));
            float n2 = __int_as_float(__builtin_amdgcn_readlane(__float_as_int(my_n), k + 2));
            float n3 = __int_as_float(__builtin_amdgcn_readlane(__float_as_int(my_n), k + 3));
            float n4 = __int_as_float(__builtin_amdgcn_readlane(__float_as_int(my_n), k + 4));
            float n5 = __int_as_float(__builtin_amdgcn_readlane(__float_as_int(my_n), k + 5));
            float n6 = __int_as_float(__builtin_amdgcn_readlane(__float_as_int(my_n), k + 6));
            float n7 = __int_as_float(__builtin_amdgcn_readlane(__float_as_int(my_n), k + 7));
            unsigned u0 = ((const unsigned*)(xb + (size_t)s0 * 128))[lane];
            unsigned u1 = ((const unsigned*)(xb + (size_t)s1 * 128))[lane];
            unsigned u2 = ((const unsigned*)(xb + (size_t)s2 * 128))[lane];
            unsigned u3 = ((const unsigned*)(xb + (size_t)s3 * 128))[lane];
            unsigned u4 = ((const unsigned*)(xb + (size_t)s4 * 128))[lane];
            unsigned u5 = ((const unsigned*)(xb + (size_t)s5 * 128))[lane];
            unsigned u6 = ((const unsigned*)(xb + (size_t)s6 * 128))[lane];
            unsigned u7 = ((const unsigned*)(xb + (size_t)s7 * 128))[lane];
            acc0.x = fmaf(__uint_as_float(u0 << 16), n0, acc0.x);
            acc0.y = fmaf(__uint_as_float(u0 & 0xffff0000u), n0, acc0.y);
            acc1.x = fmaf(__uint_as_float(u1 << 16), n1, acc1.x);
            acc1.y = fmaf(__uint_as_float(u1 & 0xffff0000u), n1, acc1.y);
            acc2.x = fmaf(__uint_as_float(u2 << 16), n2, acc2.x);
            acc2.y = fmaf(__uint_as_float(u2 & 0xffff0000u), n2, acc2.y);
            acc3.x = fmaf(__uint_as_float(u3 << 16), n3, acc3.x);
            acc3.y = fmaf(__uint_as_float(u3 & 0xffff0000u), n3, acc3.y);
            acc0.x = fmaf(__uint_as_float(u4 << 16), n4, acc0.x);
            acc0.y = fmaf(__uint_as_float(u4 & 0xffff0000u), n4, acc0.y);
            acc1.x = fmaf(__uint_as_float(u5 << 16), n5, acc1.x);
            acc1.y = fmaf(__uint_as_float(u5 & 0xffff0000u), n5, acc1.y);
            acc2.x = fmaf(__uint_as_float(u6 << 16), n6, acc2.x);
            acc2.y = fmaf(__uint_as_float(u6 & 0xffff0000u), n6, acc2.y);
            acc3.x = fmaf(__uint_as_float(u7 << 16), n7, acc3.x);
            acc3.y = fmaf(__uint_as_float(u7 & 0xffff0000u), n7, acc3.y);
        }
        for (; k + 3 < cnt; k += 4) {
            int s0 = __builtin_amdgcn_readlane(my_e, k);
            int s1 = __builtin_amdgcn_readlane(my_e, k + 1);
            int s2 = __builtin_amdgcn_readlane(my_e, k + 2);
            int s3 = __builtin_amdgcn_readlane(my_e, k + 3);
            float n0 = __int_as_float(__builtin_amdgcn_readlane(__float_as_int(my_n), k));
            float n1 = __int_as_float(__builtin_amdgcn_readlane(__float_as_int(my_n), k + 1));
            float n2 = __int_as_float(__builtin_amdgcn_readlane(__float_as_int(my_n), k + 2));
            float n3 = __int_as_float(__builtin_amdgcn_readlane(__float_as_int(my_n), k + 3));
            unsigned u0 = ((const unsigned*)(xb + (size_t)s0 * 128))[lane];
            unsigned u1 = ((const unsigned*)(xb + (size_t)s1 * 128))[lane];
            unsigned u2 = ((const unsigned*)(xb + (size_t)s2 * 128))[lane];
            unsigned u3 = ((const unsigned*)(xb + (size_t)s3 * 128))[lane];
            acc0.x = fmaf(__uint_as_float(u0 << 16), n0, acc0.x);
            acc0.y = fmaf(__uint_as_float(u0 & 0xffff0000u), n0, acc0.y);
            acc1.x = fmaf(__uint_as_float(u1 << 16), n1, acc1.x);
            acc1.y = fmaf(__uint_as_float(u1 & 0xffff0000u), n1, acc1.y);
            acc2.x = fmaf(__uint_as_float(u2 << 16), n2, acc2.x);
            acc2.y = fmaf(__uint_as_float(u2 & 0xffff0000u), n2, acc2.y);
            acc3.x = fmaf(__uint_as_float(u3 << 16), n3, acc3.x);
            acc3.y = fmaf(__uint_as_float(u3 & 0xffff0000u), n3, acc3.y);
        }
        for (; k < cnt; ++k) {
            int s0 = __builtin_amdgcn_readlane(my_e, k);
            float n0 = __int_as_float(__builtin_amdgcn_readlane(__float_as_int(my_n), k));
            unsigned u0 = ((const unsigned*)(xb + (size_t)s0 * 128))[lane];
            acc0.x = fmaf(__uint_as_float(u0 << 16), n0, acc0.x);
            acc0.y = fmaf(__uint_as_float(u0 & 0xffff0000u), n0, acc0.y);
        }
    }

    float ni = norm_in[node];
    float no = norm_out[node];
    float2 bb = ((const float2*)b1)[lane];
    float sx = (acc0.x + acc1.x) + (acc2.x + acc3.x);
    float sy = (acc0.y + acc1.y) + (acc2.y + acc3.y);
    float2 r;
    r.x = fmaxf(fmaf(sx, ni, bb.x), 0.f) * no;
    r.y = fmaxf(fmaf(sy, ni, bb.y), 0.f) * no;
    ((float2*)(out + (size_t)node * 128))[lane] = r;
}

// ---------------- pull aggregation, 64 fp16 feats, 2 edges per wave-round ----------------
__global__ __launch_bounds__(256) void pull64_kernel(const unsigned* __restrict__ x,
                                                     const int* __restrict__ row_ptr,
                                                     const int* __restrict__ bsum,
                                                     const int* __restrict__ eidx,
                                                     const float* __restrict__ b2,
                                                     const float* __restrict__ norm_in,
                                                     float* __restrict__ out) {
    int node = blockIdx.x * 4 + (threadIdx.x >> 6);
    node = __builtin_amdgcn_readfirstlane(node);
    const int lane = threadIdx.x & 63;
    const int half = lane >> 5;
    const int fl = lane & 31;
    const int beg = __builtin_amdgcn_readfirstlane(row_ptr[node] + bsum[node >> 8]);
    const int end = __builtin_amdgcn_readfirstlane(row_ptr[node + 1] + bsum[(node + 1) >> 8]);

    float2 a0 = make_float2(0.f, 0.f);
    float2 a1 = make_float2(0.f, 0.f);
    float2 a2 = make_float2(0.f, 0.f);
    float2 a3 = make_float2(0.f, 0.f);

    for (int base = beg; base < end; base += 64) {
        const int cnt = min(64, end - base);
        int my_e = (lane < cnt) ? eidx[base + lane] : 0;
        int k = 0;
        for (; k + 7 < cnt; k += 8) {
            int sa0 = __builtin_amdgcn_readlane(my_e, k);
            int sb0 = __builtin_amdgcn_readlane(my_e, k + 1);
            int sa1 = __builtin_amdgcn_readlane(my_e, k + 2);
            int sb1 = __builtin_amdgcn_readlane(my_e, k + 3);
            int sa2 = __builtin_amdgcn_readlane(my_e, k + 4);
            int sb2 = __builtin_amdgcn_readlane(my_e, k + 5);
            int sa3 = __builtin_amdgcn_readlane(my_e, k + 6);
            int sb3 = __builtin_amdgcn_readlane(my_e, k + 7);
            int e0 = half ? sb0 : sa0;
            int e1 = half ? sb1 : sa1;
            int e2 = half ? sb2 : sa2;
            int e3 = half ? sb3 : sa3;
            unsigned u0 = x[(size_t)e0 * 32 + fl];
            unsigned u1 = x[(size_t)e1 * 32 + fl];
            unsigned u2 = x[(size_t)e2 * 32 + fl];
            unsigned u3 = x[(size_t)e3 * 32 + fl];
            float2 v0 = unpack_f16x2(u0);
            float2 v1 = unpack_f16x2(u1);
            float2 v2 = unpack_f16x2(u2);
            float2 v3 = unpack_f16x2(u3);
            a0.x += v0.x; a0.y += v0.y;
            a1.x += v1.x; a1.y += v1.y;
            a2.x += v2.x; a2.y += v2.y;
            a3.x += v3.x; a3.y += v3.y;
        }
        for (; k + 1 < cnt; k += 2) {
            int sa = __builtin_amdgcn_readlane(my_e, k);
            int sb = __builtin_amdgcn_readlane(my_e, k + 1);
            int e0 = half ? sb : sa;
            unsigned u = x[(size_t)e0 * 32 + fl];
            float2 v = unpack_f16x2(u);
            a0.x += v.x; a0.y += v.y;
        }
        if (k < cnt) {
            int sa = __builtin_amdgcn_readlane(my_e, k);
            if (half == 0) {
                unsigned u = x[(size_t)sa * 32 + fl];
                float2 v = unpack_f16x2(u);
                a0.x += v.x; a0.y += v.y;
            }
        }
    }

    float ax = (a0.x + a1.x) + (a2.x + a3.x);
    float ay = (a0.y + a1.y) + (a2.y + a3.y);
    ax += __shfl_xor(ax, 32, 64);
    ay += __shfl_xor(ay, 32, 64);
    if (half == 0) {
        float ni = norm_in[node];
        float2 bb = ((const float2*)b2)[fl];
        float2 r;
        r.x = fmaxf(fmaf(ax, ni, bb.x), 0.f);
        r.y = fmaxf(fmaf(ay, ni, bb.y), 0.f);
        ((float2*)(out + (size_t)node * 64))[fl] = r;
    }
}

extern "C" void kernel_launch(void* const* d_in, const int* in_sizes, int n_in,
                              void* d_out, int out_size, void* d_ws, size_t ws_size,
                              hipStream_t stream) {
    const float* h  = (const float*)d_in[0];
    const float* W1 = (const float*)d_in[1];
    const float* b1 = (const float*)d_in[2];
    const float* W2 = (const float*)d_in[3];
    const float* b2 = (const float*)d_in[4];
    const int* src  = (const int*)d_in[5];
    const int* dst  = (const int*)d_in[6];
    float* out = (float*)d_out;

    char* ws = (char*)d_ws;
    size_t off = 0;
    auto alloc = [&](size_t bytes) {
        void* p = ws + off;
        off = (off + bytes + 255) & ~(size_t)255;
        return p;
    };
    float* norm_out   = (float*)alloc(N_NODES * sizeof(float));
    float* norm_in    = (float*)alloc(N_NODES * sizeof(float));
    int* row_ptr      = (int*)alloc((N_NODES + 1) * sizeof(int));
    int* bsum         = (int*)alloc(NBS * sizeof(int));
    unsigned short* wf_hi = (unsigned short*)alloc(2048 * 16);    // 32 KB packed W1 hi
    unsigned short* wf_lo = (unsigned short*)alloc(2048 * 16);    // 32 KB packed W1 lo
    int* eidx         = (int*)alloc((size_t)N_EDGES * sizeof(int));                       // 3.2 MB
    unsigned short* t1 = (unsigned short*)alloc((size_t)N_NODES * 128 * sizeof(short));   // 12.8 MB bf16 (reused as fp16 t2)
    float* h1p        = (float*)alloc((size_t)N_NODES * 128 * sizeof(float));             // 25.6 MB

    // hist/prefix scratch aliases into h1p (dead until pull128 writes h1p):
    unsigned char* cntD = (unsigned char*)h1p;                    // 128 * 50000 = 6.4 MB
    unsigned char* cntS = cntD + (size_t)CHUNKS * 50000;          // 6.4 MB
    unsigned char* rp   = cntS + (size_t)CHUNKS * 50000;          // 0.8 MB
    unsigned short* t2h = t1;    // t1 dead after pull128; 50000*64*2 = 6.4 MB fits

    // W1 fragment pre-pack (bf16 hi/lo planes, 64 KB, L2-resident)
    wpack_kernel<<<8, 256, 0, stream>>>(W1, wf_hi, wf_lo);

    // degree/rank histograms (LDS atomics, no global atomics)
    hist_kernel<<<CHUNKS, 1024, 0, stream>>>(src, dst, cntD, cntS, rp);

    // t1 = bf16(h @ W1) via MFMA bf16x3
    gemmA_kernel<<<GA_BLOCKS, 256, 0, stream>>>(h, wf_hi, wf_lo, t1);

    // per-node chunk prefix + norms + block scan -> partial row_ptr + bsum
    deg_scan_kernel<<<NBS, 256, 0, stream>>>(cntD, cntS, row_ptr, bsum, norm_out, norm_in);

    // scan of block sums (also writes row_ptr[N_NODES])
    scan2_kernel<<<1, 64, 0, stream>>>(bsum, row_ptr);

    // atomic-free CSR placement
    place_kernel<<<(N_EDGES + 255) / 256, 256, 0, stream>>>(src, dst, row_ptr, bsum, cntD, rp, eidx);

    // layer 1 pull (bf16 gather; per-edge norm via readlane broadcast)
    pull128_kernel<<<N_NODES / 4, 256, 0, stream>>>(t1, row_ptr, bsum, eidx, b1,
                                                    norm_in, norm_out, h1p);

    // layer 2
    gemmB_kernel<<<(N_NODES + 31) / 32, 256, 0, stream>>>(h1p, W2, t2h);
    pull64_kernel<<<N_NODES / 4, 256, 0, stream>>>((const unsigned*)t2h, row_ptr, bsum, eidx,
                                                   b2, norm_in, out);
}

// Round 9
// 211.970 us; speedup vs baseline: 1.1941x; 1.0126x over previous
//
#include <hip/hip_runtime.h>

#define N_NODES 50000
#define N_EDGES 800000
#define IN_SIZE 128
#define HIDDEN 128
#define OUT_SIZE 64

#define CHUNKS 128
#define CHUNK_EDGES 6250      // 128 * 6250 = 800000 exactly
#define NBS 196               // ceil(50000/256) block sums, granularity 256 nodes
#define GA_BLOCKS 391         // ceil(50000/128) rows, 128 rows/block (4 waves x 32)

typedef __attribute__((ext_vector_type(8))) short bf16x8;
typedef __attribute__((ext_vector_type(4))) float f32x4;

static __device__ inline unsigned short bf16_rne(float x) {
    unsigned ua = __float_as_uint(x);
    return (unsigned short)((ua + 0x7fffu + ((ua >> 16) & 1u)) >> 16);
}

static __device__ inline unsigned short f16_bits(float x) {
    _Float16 hx = (_Float16)x;
    return __builtin_bit_cast(unsigned short, hx);
}

static __device__ inline unsigned pack_f16x2(float a, float b) {
    return (unsigned)f16_bits(a) | ((unsigned)f16_bits(b) << 16);
}

static __device__ inline float2 unpack_f16x2(unsigned u) {
    _Float16 lo = __builtin_bit_cast(_Float16, (unsigned short)(u & 0xffffu));
    _Float16 hi = __builtin_bit_cast(_Float16, (unsigned short)(u >> 16));
    return make_float2((float)lo, (float)hi);
}

// ---- W1+W2 fragment pre-pack: per-lane MFMA B-frag order, bf16 hi+lo planes ----
// Bijection: lane (col=l&15, g=l>>4) slot j holds W[ks*32 + g*8 + j][ct*16 + col].
// A-frags use the same (g,j)->k map, so the MFMA dot product covers k exactly once.
__global__ __launch_bounds__(256) void wpack_kernel(const float* __restrict__ W1,
                                                    const float* __restrict__ W2,
                                                    unsigned short* __restrict__ wf_hi,
                                                    unsigned short* __restrict__ wf_lo,
                                                    unsigned short* __restrict__ wf2_hi,
                                                    unsigned short* __restrict__ wf2_lo) {
    int idx = blockIdx.x * 256 + threadIdx.x;   // 2048 W1 frags + 1024 W2 frags
    if (idx < 2048) {
        int l  = idx & 63;
        int ct = (idx >> 6) & 7;
        int ks = idx >> 9;
        int col = ct * 16 + (l & 15);
        int k0  = ks * 32 + (l >> 4) * 8;
        unsigned short hi[8], lo[8];
        #pragma unroll
        for (int j = 0; j < 8; ++j) {
            float x = W1[(size_t)(k0 + j) * 128 + col];
            unsigned short h16 = bf16_rne(x);
            hi[j] = h16;
            lo[j] = bf16_rne(x - __uint_as_float((unsigned)h16 << 16));
        }
        ((uint4*)wf_hi)[idx] = *(const uint4*)hi;
        ((uint4*)wf_lo)[idx] = *(const uint4*)lo;
    } else if (idx < 3072) {
        int i2 = idx - 2048;                    // (ks,ct,l): 4*4*64 = 1024
        int l  = i2 & 63;
        int ct = (i2 >> 6) & 3;
        int ks = i2 >> 8;
        int col = ct * 16 + (l & 15);
        int k0  = ks * 32 + (l >> 4) * 8;
        unsigned short hi[8], lo[8];
        #pragma unroll
        for (int j = 0; j < 8; ++j) {
            float x = W2[(size_t)(k0 + j) * 64 + col];
            unsigned short h16 = bf16_rne(x);
            hi[j] = h16;
            lo[j] = bf16_rne(x - __uint_as_float((unsigned)h16 << 16));
        }
        ((uint4*)wf2_hi)[i2] = *(const uint4*)hi;
        ((uint4*)wf2_lo)[i2] = *(const uint4*)lo;
    }
}

// ---------------- GEMM-A via MFMA (bf16x3): t1 = bf16(norm_out * (h @ W1)) ----------------
// 4 waves/block, 32 rows/wave (2 row-tiles of 16), 8 col-tiles, K = 4 steps of 32.
// No LDS: A from global (fp32 -> bf16 hi/lo in-register), B-frags from packed
// L2-resident Wfrag. norm_out folded into the epilogue (removes per-edge norm in pull128).
__global__ __launch_bounds__(256) void gemmA_kernel(const float* __restrict__ h,
                                                    const unsigned short* __restrict__ wf_hi,
                                                    const unsigned short* __restrict__ wf_lo,
                                                    const float* __restrict__ norm_out,
                                                    unsigned short* __restrict__ t1) {
    const int t  = threadIdx.x;
    const int wv = t >> 6;
    const int l  = t & 63;
    const int lrow = l & 15;
    const int g    = l >> 4;
    const int n0 = blockIdx.x * 128 + wv * 32;

    int r0 = n0 + lrow;      if (r0 > N_NODES - 1) r0 = N_NODES - 1;
    int r1 = n0 + 16 + lrow; if (r1 > N_NODES - 1) r1 = N_NODES - 1;
    const float* h0 = h + (size_t)r0 * 128 + g * 8;
    const float* h1 = h + (size_t)r1 * 128 + g * 8;

    f32x4 acc[2][8];
    #pragma unroll
    for (int rt = 0; rt < 2; ++rt)
        #pragma unroll
        for (int ct = 0; ct < 8; ++ct)
            acc[rt][ct] = (f32x4){0.f, 0.f, 0.f, 0.f};

    const bf16x8* bh_base = (const bf16x8*)wf_hi;
    const bf16x8* bl_base = (const bf16x8*)wf_lo;

    for (int ks = 0; ks < 4; ++ks) {
        float a0[8], a1[8];
        *(float4*)(a0)     = *(const float4*)(h0 + ks * 32);
        *(float4*)(a0 + 4) = *(const float4*)(h0 + ks * 32 + 4);
        *(float4*)(a1)     = *(const float4*)(h1 + ks * 32);
        *(float4*)(a1 + 4) = *(const float4*)(h1 + ks * 32 + 4);

        bf16x8 a0h, a0l, a1h, a1l;
        #pragma unroll
        for (int j = 0; j < 8; ++j) {
            unsigned short hh = bf16_rne(a0[j]);
            a0h[j] = (short)hh;
            a0l[j] = (short)bf16_rne(a0[j] - __uint_as_float((unsigned)hh << 16));
            unsigned short h2 = bf16_rne(a1[j]);
            a1h[j] = (short)h2;
            a1l[j] = (short)bf16_rne(a1[j] - __uint_as_float((unsigned)h2 << 16));
        }

        #pragma unroll
        for (int ct = 0; ct < 8; ++ct) {
            const int fi = (ks * 8 + ct) * 64 + l;
            bf16x8 bh = bh_base[fi];
            bf16x8 bl = bl_base[fi];
            acc[0][ct] = __builtin_amdgcn_mfma_f32_16x16x32_bf16(a0l, bh, acc[0][ct], 0, 0, 0);
            acc[0][ct] = __builtin_amdgcn_mfma_f32_16x16x32_bf16(a0h, bl, acc[0][ct], 0, 0, 0);
            acc[0][ct] = __builtin_amdgcn_mfma_f32_16x16x32_bf16(a0h, bh, acc[0][ct], 0, 0, 0);
            acc[1][ct] = __builtin_amdgcn_mfma_f32_16x16x32_bf16(a1l, bh, acc[1][ct], 0, 0, 0);
            acc[1][ct] = __builtin_amdgcn_mfma_f32_16x16x32_bf16(a1h, bl, acc[1][ct], 0, 0, 0);
            acc[1][ct] = __builtin_amdgcn_mfma_f32_16x16x32_bf16(a1h, bh, acc[1][ct], 0, 0, 0);
        }
    }

    // C/D layout (HW-verified): col = lane&15, row = (lane>>4)*4 + reg
    #pragma unroll
    for (int rt = 0; rt < 2; ++rt) {
        float no_[4];
        #pragma unroll
        for (int r = 0; r < 4; ++r) {
            int row = n0 + rt * 16 + g * 4 + r;
            no_[r] = (row < N_NODES) ? norm_out[row] : 0.f;
        }
        #pragma unroll
        for (int ct = 0; ct < 8; ++ct) {
            #pragma unroll
            for (int r = 0; r < 4; ++r) {
                int row = n0 + rt * 16 + g * 4 + r;
                if (row < N_NODES)
                    t1[(size_t)row * 128 + ct * 16 + lrow] = bf16_rne(acc[rt][ct][r] * no_[r]);
            }
        }
    }
}

// ---------------- GEMM-B via MFMA (bf16x3): t2 = fp16(h1p @ W2) ----------------
__global__ __launch_bounds__(256) void gemmB_kernel(const float* __restrict__ h1p,
                                                    const unsigned short* __restrict__ wf2_hi,
                                                    const unsigned short* __restrict__ wf2_lo,
                                                    unsigned short* __restrict__ t2h) {
    const int t  = threadIdx.x;
    const int wv = t >> 6;
    const int l  = t & 63;
    const int lrow = l & 15;
    const int g    = l >> 4;
    const int n0 = blockIdx.x * 128 + wv * 32;

    int r0 = n0 + lrow;      if (r0 > N_NODES - 1) r0 = N_NODES - 1;
    int r1 = n0 + 16 + lrow; if (r1 > N_NODES - 1) r1 = N_NODES - 1;
    const float* h0 = h1p + (size_t)r0 * 128 + g * 8;
    const float* h1 = h1p + (size_t)r1 * 128 + g * 8;

    f32x4 acc[2][4];
    #pragma unroll
    for (int rt = 0; rt < 2; ++rt)
        #pragma unroll
        for (int ct = 0; ct < 4; ++ct)
            acc[rt][ct] = (f32x4){0.f, 0.f, 0.f, 0.f};

    const bf16x8* bh_base = (const bf16x8*)wf2_hi;
    const bf16x8* bl_base = (const bf16x8*)wf2_lo;

    for (int ks = 0; ks < 4; ++ks) {
        float a0[8], a1[8];
        *(float4*)(a0)     = *(const float4*)(h0 + ks * 32);
        *(float4*)(a0 + 4) = *(const float4*)(h0 + ks * 32 + 4);
        *(float4*)(a1)     = *(const float4*)(h1 + ks * 32);
        *(float4*)(a1 + 4) = *(const float4*)(h1 + ks * 32 + 4);

        bf16x8 a0h, a0l, a1h, a1l;
        #pragma unroll
        for (int j = 0; j < 8; ++j) {
            unsigned short hh = bf16_rne(a0[j]);
            a0h[j] = (short)hh;
            a0l[j] = (short)bf16_rne(a0[j] - __uint_as_float((unsigned)hh << 16));
            unsigned short h2 = bf16_rne(a1[j]);
            a1h[j] = (short)h2;
            a1l[j] = (short)bf16_rne(a1[j] - __uint_as_float((unsigned)h2 << 16));
        }

        #pragma unroll
        for (int ct = 0; ct < 4; ++ct) {
            const int fi = (ks * 4 + ct) * 64 + l;
            bf16x8 bh = bh_base[fi];
            bf16x8 bl = bl_base[fi];
            acc[0][ct] = __builtin_amdgcn_mfma_f32_16x16x32_bf16(a0l, bh, acc[0][ct], 0, 0, 0);
            acc[0][ct] = __builtin_amdgcn_mfma_f32_16x16x32_bf16(a0h, bl, acc[0][ct], 0, 0, 0);
            acc[0][ct] = __builtin_amdgcn_mfma_f32_16x16x32_bf16(a0h, bh, acc[0][ct], 0, 0, 0);
            acc[1][ct] = __builtin_amdgcn_mfma_f32_16x16x32_bf16(a1l, bh, acc[1][ct], 0, 0, 0);
            acc[1][ct] = __builtin_amdgcn_mfma_f32_16x16x32_bf16(a1h, bl, acc[1][ct], 0, 0, 0);
            acc[1][ct] = __builtin_amdgcn_mfma_f32_16x16x32_bf16(a1h, bh, acc[1][ct], 0, 0, 0);
        }
    }

    #pragma unroll
    for (int rt = 0; rt < 2; ++rt) {
        #pragma unroll
        for (int ct = 0; ct < 4; ++ct) {
            #pragma unroll
            for (int r = 0; r < 4; ++r) {
                int row = n0 + rt * 16 + g * 4 + r;
                if (row < N_NODES)
                    t2h[(size_t)row * 64 + ct * 16 + lrow] = f16_bits(acc[rt][ct][r]);
            }
        }
    }
}

// ---- chunked LDS histogram: per-chunk dst/src counts + within-chunk rank ----
__global__ __launch_bounds__(1024) void hist_kernel(const int* __restrict__ src,
                                                    const int* __restrict__ dst,
                                                    unsigned char* __restrict__ cntD,
                                                    unsigned char* __restrict__ cntS,
                                                    unsigned char* __restrict__ rp) {
    __shared__ unsigned hD[12500];   // 50000 8-bit counters (dst)
    __shared__ unsigned hS[12500];   // 50000 8-bit counters (src)
    const int t = threadIdx.x;
    const int c = blockIdx.x;

    for (int i = t; i < 12500; i += 1024) { hD[i] = 0u; hS[i] = 0u; }
    __syncthreads();

    const int base = c * CHUNK_EDGES;
    for (int i = t; i < CHUNK_EDGES; i += 1024) {
        int e = base + i;
        int d = dst[e];
        int s = src[e];
        unsigned shd = (unsigned)(d & 3) * 8u;
        unsigned old = atomicAdd(&hD[d >> 2], 1u << shd);
        rp[e] = (unsigned char)((old >> shd) & 0xffu);   // rank within chunk
        atomicAdd(&hS[s >> 2], 1u << ((unsigned)(s & 3) * 8u));
    }
    __syncthreads();

    unsigned* gD = (unsigned*)cntD + (size_t)c * 12500;
    unsigned* gS = (unsigned*)cntS + (size_t)c * 12500;
    for (int i = t; i < 12500; i += 1024) { gD[i] = hD[i]; gS[i] = hS[i]; }
}

// ---- fused: per-node chunk prefix (in-place) + norms + block-level scan ----
__global__ __launch_bounds__(256) void deg_scan_kernel(unsigned char* __restrict__ cntD,
                                                       const unsigned char* __restrict__ cntS,
                                                       int* __restrict__ row_ptr,
                                                       int* __restrict__ bsum,
                                                       float* __restrict__ norm_out,
                                                       float* __restrict__ norm_in) {
    const int t = threadIdx.x, lane = t & 63, w = t >> 6;
    const int n = blockIdx.x * 256 + t;
    unsigned sumD = 0u, sumS = 0u;
    if (n < N_NODES) {
        #pragma unroll 4
        for (int c = 0; c < CHUNKS; ++c) {
            size_t idx = (size_t)c * 50000 + n;
            unsigned v = cntD[idx];
            cntD[idx] = (unsigned char)sumD;   // exclusive prefix (total deg < 256)
            sumD += v;
            sumS += cntS[idx];
        }
        norm_in[n]  = rsqrtf((float)(sumD ? sumD : 1u));
        norm_out[n] = rsqrtf((float)(sumS ? sumS : 1u));
    }
    __shared__ int wsum[4];
    int v = (n < N_NODES) ? (int)sumD : 0;
    int incl = v;
    #pragma unroll
    for (int d = 1; d < 64; d <<= 1) {
        int u = __shfl_up(incl, d, 64);
        if (lane >= d) incl += u;
    }
    if (lane == 63) wsum[w] = incl;
    __syncthreads();
    int woff = 0, total = 0;
    #pragma unroll
    for (int j = 0; j < 4; ++j) {
        int s = wsum[j];
        if (j < w) woff += s;
        total += s;
    }
    if (n < N_NODES) row_ptr[n] = woff + incl - v;
    if (t == 0) bsum[blockIdx.x] = total;
}

// ---- scan of 196 block sums (single wave, chunks with carry) ----
__global__ __launch_bounds__(64) void scan2_kernel(int* __restrict__ bsum,
                                                   int* __restrict__ row_ptr) {
    const int lane = threadIdx.x;
    int carry = 0;
    for (int base = 0; base < NBS; base += 64) {
        int t = base + lane;
        int v = (t < NBS) ? bsum[t] : 0;
        int incl = v;
        #pragma unroll
        for (int d = 1; d < 64; d <<= 1) {
            int u = __shfl_up(incl, d, 64);
            if (lane >= d) incl += u;
        }
        int excl = carry + incl - v;
        if (t < NBS) bsum[t] = excl;
        if (t == NBS - 1) row_ptr[N_NODES] = N_EDGES - excl;
        carry += __shfl(incl, 63, 64);
    }
}

// ---- atomic-free CSR placement: row_ptr + bsum + chunk prefix + rank ----
__global__ __launch_bounds__(256) void place_kernel(const int* __restrict__ src,
                                                    const int* __restrict__ dst,
                                                    const int* __restrict__ row_ptr,
                                                    const int* __restrict__ bsum,
                                                    const unsigned char* __restrict__ cntD,
                                                    const unsigned char* __restrict__ rp,
                                                    int* __restrict__ eidx) {
    int e = blockIdx.x * 256 + threadIdx.x;
    if (e < N_EDGES) {
        int d = dst[e];
        int c = e / CHUNK_EDGES;
        int pos = row_ptr[d] + bsum[d >> 8] + (int)cntD[(size_t)c * 50000 + d] + (int)rp[e];
        eidx[pos] = src[e];
    }
}

// ---------------- pull aggregation, 128 bf16 feats: one wave per node ----------------
// norm_out pre-folded into t1 -> pure gather+add. One vector eidx load per 64
// edges, per-edge broadcast via v_readlane, unroll 8 -> 8 gathers in flight.
__global__ __launch_bounds__(256) void pull128_kernel(const unsigned short* __restrict__ xb,
                                                      const int* __restrict__ row_ptr,
                                                      const int* __restrict__ bsum,
                                                      const int* __restrict__ eidx,
                                                      const float* __restrict__ b1,
                                                      const float* __restrict__ norm_in,
                                                      const float* __restrict__ norm_out,
                                                      float* __restrict__ out) {
    int node = blockIdx.x * 4 + (threadIdx.x >> 6);
    node = __builtin_amdgcn_readfirstlane(node);
    const int lane = threadIdx.x & 63;
    const int beg = __builtin_amdgcn_readfirstlane(row_ptr[node] + bsum[node >> 8]);
    const int end = __builtin_amdgcn_readfirstlane(row_ptr[node + 1] + bsum[(node + 1) >> 8]);

    float2 acc0 = make_float2(0.f, 0.f);
    float2 acc1 = make_float2(0.f, 0.f);
    float2 acc2 = make_float2(0.f, 0.f);
    float2 acc3 = make_float2(0.f, 0.f);

    for (int base = beg; base < end; base += 64) {
        const int cnt = min(64, end - base);
        int my_e = (lane < cnt) ? eidx[base + lane] : 0;
        int k = 0;
        for (; k + 7 < cnt; k += 8) {
            int s0 = __builtin_amdgcn_readlane(my_e, k);
            int s1 = __builtin_amdgcn_readlane(my_e, k + 1);
            int s2 = __builtin_amdgcn_readlane(my_e, k + 2);
            int s3 = __builtin_amdgcn_readlane(my_e, k + 3);
            int s4 = __builtin_amdgcn_readlane(my_e, k + 4);
            int s5 = __builtin_amdgcn_readlane(my_e, k + 5);
            int s6 = __builtin_amdgcn_readlane(my_e, k + 6);
            int s7 = __builtin_amdgcn_readlane(my_e, k + 7);
            unsigned u0 = ((const unsigned*)(xb + (size_t)s0 * 128))[lane];
            unsigned u1 = ((const unsigned*)(xb + (size_t)s1 * 128))[lane];
            unsigned u2 = ((const unsigned*)(xb + (size_t)s2 * 128))[lane];
            unsigned u3 = ((const unsigned*)(xb + (size_t)s3 * 128))[lane];
            unsigned u4 = ((const unsigned*)(xb + (size_t)s4 * 128))[lane];
            unsigned u5 = ((const unsigned*)(xb + (size_t)s5 * 128))[lane];
            unsigned u6 = ((const unsigned*)(xb + (size_t)s6 * 128))[lane];
            unsigned u7 = ((const unsigned*)(xb + (size_t)s7 * 128))[lane];
            acc0.x += __uint_as_float(u0 << 16);
            acc0.y += __uint_as_float(u0 & 0xffff0000u);
            acc1.x += __uint_as_float(u1 << 16);
            acc1.y += __uint_as_float(u1 & 0xffff0000u);
            acc2.x += __uint_as_float(u2 << 16);
            acc2.y += __uint_as_float(u2 & 0xffff0000u);
            acc3.x += __uint_as_float(u3 << 16);
            acc3.y += __uint_as_float(u3 & 0xffff0000u);
            acc0.x += __uint_as_float(u4 << 16);
            acc0.y += __uint_as_float(u4 & 0xffff0000u);
            acc1.x += __uint_as_float(u5 << 16);
            acc1.y += __uint_as_float(u5 & 0xffff0000u);
            acc2.x += __uint_as_float(u6 << 16);
            acc2.y += __uint_as_float(u6 & 0xffff0000u);
            acc3.x += __uint_as_float(u7 << 16);
            acc3.y += __uint_as_float(u7 & 0xffff0000u);
        }
        for (; k + 3 < cnt; k += 4) {
            int s0 = __builtin_amdgcn_readlane(my_e, k);
            int s1 = __builtin_amdgcn_readlane(my_e, k + 1);
            int s2 = __builtin_amdgcn_readlane(my_e, k + 2);
            int s3 = __builtin_amdgcn_readlane(my_e, k + 3);
            unsigned u0 = ((const unsigned*)(xb + (size_t)s0 * 128))[lane];
            unsigned u1 = ((const unsigned*)(xb + (size_t)s1 * 128))[lane];
            unsigned u2 = ((const unsigned*)(xb + (size_t)s2 * 128))[lane];
            unsigned u3 = ((const unsigned*)(xb + (size_t)s3 * 128))[lane];
            acc0.x += __uint_as_float(u0 << 16);
            acc0.y += __uint_as_float(u0 & 0xffff0000u);
            acc1.x += __uint_as_float(u1 << 16);
            acc1.y += __uint_as_float(u1 & 0xffff0000u);
            acc2.x += __uint_as_float(u2 << 16);
            acc2.y += __uint_as_float(u2 & 0xffff0000u);
            acc3.x += __uint_as_float(u3 << 16);
            acc3.y += __uint_as_float(u3 & 0xffff0000u);
        }
        for (; k < cnt; ++k) {
            int s0 = __builtin_amdgcn_readlane(my_e, k);
            unsigned u0 = ((const unsigned*)(xb + (size_t)s0 * 128))[lane];
            acc0.x += __uint_as_float(u0 << 16);
            acc0.y += __uint_as_float(u0 & 0xffff0000u);
        }
    }

    float ni = norm_in[node];
    float no = norm_out[node];
    float2 bb = ((const float2*)b1)[lane];
    float sx = (acc0.x + acc1.x) + (acc2.x + acc3.x);
    float sy = (acc0.y + acc1.y) + (acc2.y + acc3.y);
    float2 r;
    r.x = fmaxf(fmaf(sx, ni, bb.x), 0.f) * no;
    r.y = fmaxf(fmaf(sy, ni, bb.y), 0.f) * no;
    ((float2*)(out + (size_t)node * 128))[lane] = r;
}

// ---------------- pull aggregation, 64 fp16 feats, 2 edges per wave-round ----------------
__global__ __launch_bounds__(256) void pull64_kernel(const unsigned* __restrict__ x,
                                                     const int* __restrict__ row_ptr,
                                                     const int* __restrict__ bsum,
                                                     const int* __restrict__ eidx,
                                                     const float* __restrict__ b2,
                                                     const float* __restrict__ norm_in,
                                                     float* __restrict__ out) {
    int node = blockIdx.x * 4 + (threadIdx.x >> 6);
    node = __builtin_amdgcn_readfirstlane(node);
    const int lane = threadIdx.x & 63;
    const int half = lane >> 5;
    const int fl = lane & 31;
    const int beg = __builtin_amdgcn_readfirstlane(row_ptr[node] + bsum[node >> 8]);
    const int end = __builtin_amdgcn_readfirstlane(row_ptr[node + 1] + bsum[(node + 1) >> 8]);

    float2 a0 = make_float2(0.f, 0.f);
    float2 a1 = make_float2(0.f, 0.f);
    float2 a2 = make_float2(0.f, 0.f);
    float2 a3 = make_float2(0.f, 0.f);

    for (int base = beg; base < end; base += 64) {
        const int cnt = min(64, end - base);
        int my_e = (lane < cnt) ? eidx[base + lane] : 0;
        int k = 0;
        for (; k + 7 < cnt; k += 8) {
            int sa0 = __builtin_amdgcn_readlane(my_e, k);
            int sb0 = __builtin_amdgcn_readlane(my_e, k + 1);
            int sa1 = __builtin_amdgcn_readlane(my_e, k + 2);
            int sb1 = __builtin_amdgcn_readlane(my_e, k + 3);
            int sa2 = __builtin_amdgcn_readlane(my_e, k + 4);
            int sb2 = __builtin_amdgcn_readlane(my_e, k + 5);
            int sa3 = __builtin_amdgcn_readlane(my_e, k + 6);
            int sb3 = __builtin_amdgcn_readlane(my_e, k + 7);
            int e0 = half ? sb0 : sa0;
            int e1 = half ? sb1 : sa1;
            int e2 = half ? sb2 : sa2;
            int e3 = half ? sb3 : sa3;
            unsigned u0 = x[(size_t)e0 * 32 + fl];
            unsigned u1 = x[(size_t)e1 * 32 + fl];
            unsigned u2 = x[(size_t)e2 * 32 + fl];
            unsigned u3 = x[(size_t)e3 * 32 + fl];
            float2 v0 = unpack_f16x2(u0);
            float2 v1 = unpack_f16x2(u1);
            float2 v2 = unpack_f16x2(u2);
            float2 v3 = unpack_f16x2(u3);
            a0.x += v0.x; a0.y += v0.y;
            a1.x += v1.x; a1.y += v1.y;
            a2.x += v2.x; a2.y += v2.y;
            a3.x += v3.x; a3.y += v3.y;
        }
        for (; k + 1 < cnt; k += 2) {
            int sa = __builtin_amdgcn_readlane(my_e, k);
            int sb = __builtin_amdgcn_readlane(my_e, k + 1);
            int e0 = half ? sb : sa;
            unsigned u = x[(size_t)e0 * 32 + fl];
            float2 v = unpack_f16x2(u);
            a0.x += v.x; a0.y += v.y;
        }
        if (k < cnt) {
            int sa = __builtin_amdgcn_readlane(my_e, k);
            if (half == 0) {
                unsigned u = x[(size_t)sa * 32 + fl];
                float2 v = unpack_f16x2(u);
                a0.x += v.x; a0.y += v.y;
            }
        }
    }

    float ax = (a0.x + a1.x) + (a2.x + a3.x);
    float ay = (a0.y + a1.y) + (a2.y + a3.y);
    ax += __shfl_xor(ax, 32, 64);
    ay += __shfl_xor(ay, 32, 64);
    if (half == 0) {
        float ni = norm_in[node];
        float2 bb = ((const float2*)b2)[fl];
        float2 r;
        r.x = fmaxf(fmaf(ax, ni, bb.x), 0.f);
        r.y = fmaxf(fmaf(ay, ni, bb.y), 0.f);
        ((float2*)(out + (size_t)node * 64))[fl] = r;
    }
}

extern "C" void kernel_launch(void* const* d_in, const int* in_sizes, int n_in,
                              void* d_out, int out_size, void* d_ws, size_t ws_size,
                              hipStream_t stream) {
    const float* h  = (const float*)d_in[0];
    const float* W1 = (const float*)d_in[1];
    const float* b1 = (const float*)d_in[2];
    const float* W2 = (const float*)d_in[3];
    const float* b2 = (const float*)d_in[4];
    const int* src  = (const int*)d_in[5];
    const int* dst  = (const int*)d_in[6];
    float* out = (float*)d_out;

    char* ws = (char*)d_ws;
    size_t off = 0;
    auto alloc = [&](size_t bytes) {
        void* p = ws + off;
        off = (off + bytes + 255) & ~(size_t)255;
        return p;
    };
    float* norm_out   = (float*)alloc(N_NODES * sizeof(float));
    float* norm_in    = (float*)alloc(N_NODES * sizeof(float));
    int* row_ptr      = (int*)alloc((N_NODES + 1) * sizeof(int));
    int* bsum         = (int*)alloc(NBS * sizeof(int));
    unsigned short* wf_hi  = (unsigned short*)alloc(2048 * 16);   // 32 KB packed W1 hi
    unsigned short* wf_lo  = (unsigned short*)alloc(2048 * 16);   // 32 KB packed W1 lo
    unsigned short* wf2_hi = (unsigned short*)alloc(1024 * 16);   // 16 KB packed W2 hi
    unsigned short* wf2_lo = (unsigned short*)alloc(1024 * 16);   // 16 KB packed W2 lo
    int* eidx         = (int*)alloc((size_t)N_EDGES * sizeof(int));                       // 3.2 MB
    unsigned short* t1 = (unsigned short*)alloc((size_t)N_NODES * 128 * sizeof(short));   // 12.8 MB bf16 (reused as fp16 t2)
    float* h1p        = (float*)alloc((size_t)N_NODES * 128 * sizeof(float));             // 25.6 MB

    // hist/prefix scratch aliases into h1p (dead until pull128 writes h1p):
    unsigned char* cntD = (unsigned char*)h1p;                    // 128 * 50000 = 6.4 MB
    unsigned char* cntS = cntD + (size_t)CHUNKS * 50000;          // 6.4 MB
    unsigned char* rp   = cntS + (size_t)CHUNKS * 50000;          // 0.8 MB
    unsigned short* t2h = t1;    // t1 dead after pull128; 50000*64*2 = 6.4 MB fits

    // W1+W2 fragment pre-pack (bf16 hi/lo planes, L2-resident)
    wpack_kernel<<<12, 256, 0, stream>>>(W1, W2, wf_hi, wf_lo, wf2_hi, wf2_lo);

    // degree/rank histograms (LDS atomics, no global atomics)
    hist_kernel<<<CHUNKS, 1024, 0, stream>>>(src, dst, cntD, cntS, rp);

    // per-node chunk prefix + norms + block scan -> partial row_ptr + bsum
    deg_scan_kernel<<<NBS, 256, 0, stream>>>(cntD, cntS, row_ptr, bsum, norm_out, norm_in);

    // scan of block sums (also writes row_ptr[N_NODES])
    scan2_kernel<<<1, 64, 0, stream>>>(bsum, row_ptr);

    // atomic-free CSR placement
    place_kernel<<<(N_EDGES + 255) / 256, 256, 0, stream>>>(src, dst, row_ptr, bsum, cntD, rp, eidx);

    // t1 = bf16(norm_out * (h @ W1)) via MFMA bf16x3 (norm folded)
    gemmA_kernel<<<GA_BLOCKS, 256, 0, stream>>>(h, wf_hi, wf_lo, norm_out, t1);

    // layer 1 pull (pure bf16 gather+add)
    pull128_kernel<<<N_NODES / 4, 256, 0, stream>>>(t1, row_ptr, bsum, eidx, b1,
                                                    norm_in, norm_out, h1p);

    // layer 2
    gemmB_kernel<<<GA_BLOCKS, 256, 0, stream>>>(h1p, wf2_hi, wf2_lo, t2h);
    pull64_kernel<<<N_NODES / 4, 256, 0, stream>>>((const unsigned*)t2h, row_ptr, bsum, eidx,
                                                   b2, norm_in, out);
}